// Round 4
// baseline (105.212 us; speedup 1.0000x reference)
//
#include <hip/hip_runtime.h>

typedef __attribute__((ext_vector_type(8))) short bf16x8;
typedef __attribute__((ext_vector_type(4))) float f32x4;

constexpr int N_PTS = 16384;
constexpr int KN = 16;    // neighbors
constexpr int P  = 15;    // kernel points
constexpr int CI = 64;
constexpr int CO = 128;
constexpr int QB = 16;    // query points per block (agg kernel)
constexpr int KTOT   = P * CI;     // 960
constexpr int KSTEPS = KTOT / 32;  // 30
constexpr int NTILES = CO / 16;    // 8
// ws layout: WB fragments [0, 245760) bytes; agg bf16 at byte 262144
constexpr size_t AGG_BYTE_OFF = 262144;

static __device__ __forceinline__ unsigned short f2bf(float f) {
    unsigned u = __float_as_uint(f);
    u = (u + 0x7fffu + ((u >> 16) & 1u)) >> 16;  // RNE
    return (unsigned short)u;
}

static __device__ __forceinline__ void gload16(const void* g, void* l) {
    __builtin_amdgcn_global_load_lds(
        (const __attribute__((address_space(1))) unsigned*)g,
        (__attribute__((address_space(3))) unsigned*)l, 16, 0, 0);
}

// ---- Kernel 1: influences + neighbor aggregation -> agg bf16 [N][960] ----
// Blocks 0..59 additionally convert W -> bf16 B-fragments WB[kstep][ntile][lane][8].
__global__ __launch_bounds__(256) void kpconv_agg(
    const float* __restrict__ query,    // [N][3]
    const float* __restrict__ support,  // [M][3]
    const int*   __restrict__ nidx,     // [N][KN]
    const float* __restrict__ feats,    // [M][CI]
    const float* __restrict__ W,        // [P][CI][CO]
    const float* __restrict__ kp,       // [P][3]
    unsigned short* __restrict__ WB,    // out: bf16 fragments (122880 elems)
    unsigned short* __restrict__ aggG)  // out: bf16 [N][KTOT]
{
    // ---- embedded W prep (60 blocks cover 15360 fragment-rows) ----
    if (blockIdx.x < 60) {
        const int t = blockIdx.x * 256 + threadIdx.x;
        const int s  = t >> 9;
        const int nt = (t >> 6) & 7;
        const int l  = t & 63;
        const int kb = s * 32 + ((l >> 4) * 8);
        const int o  = nt * 16 + (l & 15);
        unsigned short v[8];
        #pragma unroll
        for (int j = 0; j < 8; ++j) v[j] = f2bf(W[(size_t)(kb + j) * CO + o]);
        uint4 q;
        q.x = v[0] | ((unsigned)v[1] << 16);
        q.y = v[2] | ((unsigned)v[3] << 16);
        q.z = v[4] | ((unsigned)v[5] << 16);
        q.w = v[6] | ((unsigned)v[7] << 16);
        *(uint4*)&WB[(size_t)t * 8] = q;
    }

    __shared__ float sKp[P][3];
    __shared__ int   sIdx[QB][KN];
    __shared__ __align__(16) float sInfl[QB][KN][16];

    const int t  = threadIdx.x;
    const int n0 = blockIdx.x * QB;

    if (t < P * 3) ((float*)sKp)[t] = kp[t];
    __syncthreads();

    // ---- Phase A: one thread per (pt, k) ----
    {
        const int pt = t >> 4, k = t & 15;
        const int n = n0 + pt;
        const int idx = nidx[n * KN + k];
        sIdx[pt][k] = idx;
        const float rx = support[idx * 3 + 0] - query[n * 3 + 0];
        const float ry = support[idx * 3 + 1] - query[n * 3 + 1];
        const float rz = support[idx * 3 + 2] - query[n * 3 + 2];
        #pragma unroll
        for (int p = 0; p < P; ++p) {
            const float dx = rx - sKp[p][0];
            const float dy = ry - sKp[p][1];
            const float dz = rz - sKp[p][2];
            sInfl[pt][k][p] = fmaxf(1.0f - sqrtf(dx*dx + dy*dy + dz*dz), 0.0f);
        }
        sInfl[pt][k][15] = 0.0f;
    }
    __syncthreads();

    // ---- Phase B: thread (pt = t>>4, c = (t&15)*4): agg[n][p*64 + c..c+3] ----
    {
        const int pt = t >> 4;
        const int c  = (t & 15) * 4;
        int idxv[KN];
        {
            const int4* ip = (const int4*)sIdx[pt];
            #pragma unroll
            for (int k4 = 0; k4 < 4; ++k4) {
                const int4 v = ip[k4];
                idxv[k4*4+0] = v.x; idxv[k4*4+1] = v.y;
                idxv[k4*4+2] = v.z; idxv[k4*4+3] = v.w;
            }
        }
        float acc[P][4];
        #pragma unroll
        for (int p = 0; p < P; ++p)
            #pragma unroll
            for (int j = 0; j < 4; ++j) acc[p][j] = 0.0f;

        #pragma unroll
        for (int k = 0; k < KN; ++k) {
            const float4 f = *(const float4*)&feats[(size_t)idxv[k] * CI + c];
            float iv[16];
            {
                const float4* ip = (const float4*)sInfl[pt][k];  // broadcast reads
                *(float4*)&iv[0]  = ip[0];
                *(float4*)&iv[4]  = ip[1];
                *(float4*)&iv[8]  = ip[2];
                *(float4*)&iv[12] = ip[3];
            }
            #pragma unroll
            for (int p = 0; p < P; ++p) {
                acc[p][0] = fmaf(iv[p], f.x, acc[p][0]);
                acc[p][1] = fmaf(iv[p], f.y, acc[p][1]);
                acc[p][2] = fmaf(iv[p], f.z, acc[p][2]);
                acc[p][3] = fmaf(iv[p], f.w, acc[p][3]);
            }
        }
        const size_t rowBase = (size_t)(n0 + pt) * KTOT;
        #pragma unroll
        for (int p = 0; p < P; ++p) {
            uint2 w;
            w.x = f2bf(acc[p][0]) | ((unsigned)f2bf(acc[p][1]) << 16);
            w.y = f2bf(acc[p][2]) | ((unsigned)f2bf(acc[p][3]) << 16);
            *(uint2*)&aggG[rowBase + p * CI + c] = w;  // coalesced 128B/16 lanes
        }
    }
}

// ---- Kernel 2: out[16384][128] = agg[16384][960] @ W[960][128], bf16 MFMA ----
// BM=64, grid 256 blocks x 512 threads (8 waves). Double-buffered LDS.
__global__ __launch_bounds__(512) void kpconv_gemm(
    const unsigned short* __restrict__ aggG,  // bf16 [N][KTOT]
    const unsigned short* __restrict__ WB,    // fragments [kstep][ntile][64][8]
    float* __restrict__ out)                  // [N][CO]
{
    // sA: [buf][q(0..3)][row(0..63)][8 bf16]  (column-quarter-major, 4 KB/buf)
    // sB: [buf][ntile(0..7)][lane(0..63)][8 bf16]                    (8 KB/buf)
    __shared__ __align__(16) unsigned short sA[2][4 * 64 * 8];
    __shared__ __align__(16) unsigned short sB[2][8 * 64 * 8];

    const int t = threadIdx.x;
    const int w = t >> 6, l = t & 63;
    const int n0 = blockIdx.x * 64;

    // compute roles
    const int rt = w & 3;        // row-tile (16 rows)
    const int ng = w >> 2;       // ntile group (4 ntiles)
    const int q  = l >> 4;       // k-quarter for A-frag

    f32x4 acc[4] = {{0.f,0.f,0.f,0.f},{0.f,0.f,0.f,0.f},
                    {0.f,0.f,0.f,0.f},{0.f,0.f,0.f,0.f}};

    // ---- staging: waves 0-3 stage A (1 chunk/lane), waves 4-7 stage B (2) ----
    #define STAGE(s, b)                                                        \
        do {                                                                   \
            if (w < 4) {                                                       \
                gload16(&aggG[(size_t)(n0 + l) * KTOT + (s) * 32 + w * 8],     \
                        &sA[b][w * 512]);                                      \
            } else {                                                           \
                const int j = w - 4;                                           \
                gload16(&WB[((size_t)(s) * 512 + j * 64 + l) * 8],             \
                        &sB[b][j * 512]);                                      \
                gload16(&WB[((size_t)(s) * 512 + (j + 4) * 64 + l) * 8],       \
                        &sB[b][(j + 4) * 512]);                                \
            }                                                                  \
        } while (0)

    STAGE(0, 0);
    int b = 0;
    for (int s = 0; s < KSTEPS; ++s) {
        __syncthreads();                 // drains vmcnt -> stage(s) landed
        if (s + 1 < KSTEPS) STAGE(s + 1, b ^ 1);
        const bf16x8 a = *(const bf16x8*)&sA[b][q * 512 + (rt * 16 + (l & 15)) * 8];
        #pragma unroll
        for (int nt = 0; nt < 4; ++nt) {
            const bf16x8 bb = *(const bf16x8*)&sB[b][(ng * 4 + nt) * 512 + l * 8];
            acc[nt] = __builtin_amdgcn_mfma_f32_16x16x32_bf16(a, bb, acc[nt], 0, 0, 0);
        }
        b ^= 1;
    }
    #undef STAGE

    // ---- epilogue: C/D layout col=l&15, row=(l>>4)*4+j ----
    const int colBase = ng * 64;
    const int rowBase = n0 + rt * 16 + (l >> 4) * 4;
    #pragma unroll
    for (int nt = 0; nt < 4; ++nt) {
        #pragma unroll
        for (int j = 0; j < 4; ++j) {
            out[(size_t)(rowBase + j) * CO + colBase + nt * 16 + (l & 15)] = acc[nt][j];
        }
    }
}

extern "C" void kernel_launch(void* const* d_in, const int* in_sizes, int n_in,
                              void* d_out, int out_size, void* d_ws, size_t ws_size,
                              hipStream_t stream) {
    const float* query   = (const float*)d_in[0];
    const float* support = (const float*)d_in[1];
    const int*   nidx    = (const int*)d_in[2];
    const float* feats   = (const float*)d_in[3];
    const float* W       = (const float*)d_in[4];
    const float* kp      = (const float*)d_in[5];
    float* out = (float*)d_out;

    unsigned short* WB   = (unsigned short*)d_ws;
    unsigned short* aggG = (unsigned short*)((char*)d_ws + AGG_BYTE_OFF);

    hipLaunchKernelGGL(kpconv_agg, dim3(N_PTS / QB), dim3(256), 0, stream,
                       query, support, nidx, feats, W, kp, WB, aggG);
    hipLaunchKernelGGL(kpconv_gemm, dim3(N_PTS / 64), dim3(512), 0, stream,
                       aggG, WB, out);
}

// Round 6
// 96.892 us; speedup vs baseline: 1.0859x; 1.0859x over previous
//
#include <hip/hip_runtime.h>

typedef __attribute__((ext_vector_type(8))) short bf16x8;
typedef __attribute__((ext_vector_type(4))) float f32x4;

constexpr int N_PTS = 16384;
constexpr int KN = 16;    // neighbors
constexpr int P  = 15;    // kernel points
constexpr int CI = 64;
constexpr int CO = 128;
constexpr int QB = 16;    // query points per block
constexpr int KP = 1024;           // padded K' (16 values per producer lane * 64 lanes)
constexpr int KSTEPS = KP / 32;    // 32
constexpr int IPITCH = 32;         // shorts per sInflT row (k = 0..31, zeros above 15)
constexpr int APITCH = KP + 8;     // 1032 shorts per sAgg row (bank-conflict pad)

static __device__ __forceinline__ unsigned short f2bf(float f) {
    unsigned u = __float_as_uint(f);
    u = (u + 0x7fffu + ((u >> 16) & 1u)) >> 16;  // RNE
    return (unsigned short)u;
}

static __device__ __forceinline__ unsigned cvt_pk_bf16(float lo, float hi) {
    unsigned r;
    asm("v_cvt_pk_bf16_f32 %0, %1, %2" : "=v"(r) : "v"(lo), "v"(hi));
    return r;
}

// ---- Prep: W fp32 [P][CI][CO] -> bf16 B-fragments WB[kstep][ntile][lane][8]
// in the permuted K' order: k' = prodlane*16 + ct*4 + jr,
// where p = (prodlane>>4)*4 + jr, c = (prodlane&15) + 16*ct; p==15 rows are 0.
__global__ __launch_bounds__(256) void prep_w(const float* __restrict__ W,
                                              unsigned short* __restrict__ WB) {
    const int t = blockIdx.x * 256 + threadIdx.x;   // 32*8*64 = 16384 total
    const int s  = t >> 9;          // kstep 0..31
    const int nt = (t >> 6) & 7;    // ntile
    const int l  = t & 63;          // lane
    const int q  = l >> 4;
    const int o  = nt * 16 + (l & 15);
    unsigned short v[8];
    #pragma unroll
    for (int j = 0; j < 8; ++j) {
        const int kp_ = s * 32 + q * 8 + j;
        const int prodlane = kp_ >> 4;
        const int ct = (kp_ >> 2) & 3;
        const int jr = kp_ & 3;
        const int p  = (prodlane >> 4) * 4 + jr;
        const int c  = (prodlane & 15) + ct * 16;
        v[j] = (p < P) ? f2bf(W[(size_t)(p * CI + c) * CO + o]) : (unsigned short)0;
    }
    uint4 qv;
    qv.x = v[0] | ((unsigned)v[1] << 16);
    qv.y = v[2] | ((unsigned)v[3] << 16);
    qv.z = v[4] | ((unsigned)v[5] << 16);
    qv.w = v[6] | ((unsigned)v[7] << 16);
    *(uint4*)&WB[(size_t)t * 8] = qv;
}

__global__ __launch_bounds__(256) void kpconv_fused(
    const float* __restrict__ query,    // [N][3]
    const float* __restrict__ support,  // [M][3]
    const int*   __restrict__ nidx,     // [N][KN]
    const float* __restrict__ feats,    // [M][CI]
    const unsigned short* __restrict__ WB,
    const float* __restrict__ kp,       // [P][3]
    float* __restrict__ out)            // [N][CO]
{
    __shared__ float sKp[P][3];
    __shared__ int   sIdx[QB][KN];
    __shared__ __align__(16) unsigned short sInflT[QB * 16 * IPITCH]; // 16 KB
    __shared__ __align__(16) unsigned short sAgg[QB * APITCH];       // 33 KB

    const int t  = threadIdx.x;
    const int n0 = blockIdx.x * QB;
    const int l  = t & 63, w = t >> 6, q = l >> 4;

    if (t < P * 3) ((float*)sKp)[t] = kp[t];

    // zero-init sInflT (16384 B = 1024 uint4, 4 per thread)
    {
        const uint4 z = {0u, 0u, 0u, 0u};
        uint4* dst = (uint4*)sInflT;
        dst[t] = z; dst[t + 256] = z; dst[t + 512] = z; dst[t + 768] = z;
    }
    __syncthreads();

    // ---- Phase A: thread (pt = t>>4, k = t&15): infl -> bf16 sInflT[pt][p][k]
    {
        const int pt = t >> 4, k = t & 15;
        const int n = n0 + pt;
        const int idx = nidx[n * KN + k];
        sIdx[pt][k] = idx;
        const float rx = support[idx * 3 + 0] - query[n * 3 + 0];
        const float ry = support[idx * 3 + 1] - query[n * 3 + 1];
        const float rz = support[idx * 3 + 2] - query[n * 3 + 2];
        unsigned short* row0 = &sInflT[(pt * 16) * IPITCH + k];
        #pragma unroll
        for (int p = 0; p < P; ++p) {
            const float dx = rx - sKp[p][0];
            const float dy = ry - sKp[p][1];
            const float dz = rz - sKp[p][2];
            const float infl = fmaxf(1.0f - sqrtf(dx*dx + dy*dy + dz*dz), 0.0f);
            row0[p * IPITCH] = f2bf(infl);
        }
        // p = 15 row and k in [16,32) stay zero from the memset.
    }
    __syncthreads();

    // ---- Phase B: wave w computes agg for pts w*4 .. w*4+3 via MFMA ----
    // A = infl[p][k] (zeros for k>=16), B[k][c] = feats gathered (zeros k>=16).
    {
        const f32x4 zero4 = {0.f, 0.f, 0.f, 0.f};
        for (int i = 0; i < 4; ++i) {
            const int pt = w * 4 + i;
            const bf16x8 a = *(const bf16x8*)&sInflT[(pt * 16 + (l & 15)) * IPITCH + q * 8];
            // gather feats fp32: lane covers c = (l&15) + 16*ct, rows k = (q&1)*8 + j
            float fv[4][8];
            #pragma unroll
            for (int j = 0; j < 8; ++j) {
                const int idx = sIdx[pt][(q & 1) * 8 + j];   // LDS broadcast
                const float* rowp = feats + (size_t)idx * CI + (l & 15);
                #pragma unroll
                for (int ct = 0; ct < 4; ++ct) fv[ct][j] = rowp[ct * 16];
            }
            f32x4 aggv[4];
            #pragma unroll
            for (int ct = 0; ct < 4; ++ct) {
                unsigned b0 = cvt_pk_bf16(fv[ct][0], fv[ct][1]);
                unsigned b1 = cvt_pk_bf16(fv[ct][2], fv[ct][3]);
                unsigned b2 = cvt_pk_bf16(fv[ct][4], fv[ct][5]);
                unsigned b3 = cvt_pk_bf16(fv[ct][6], fv[ct][7]);
                if (l >= 32) { b0 = 0; b1 = 0; b2 = 0; b3 = 0; }  // k >= 16 half
                union { unsigned u[4]; bf16x8 v; } bu;
                bu.u[0] = b0; bu.u[1] = b1; bu.u[2] = b2; bu.u[3] = b3;
                aggv[ct] = __builtin_amdgcn_mfma_f32_16x16x32_bf16(a, bu.v, zero4, 0, 0, 0);
            }
            // write 16 values at k' = l*16 + ct*4 + jr  (contiguous per lane)
            uint4 w0, w1;
            w0.x = cvt_pk_bf16(aggv[0][0], aggv[0][1]);
            w0.y = cvt_pk_bf16(aggv[0][2], aggv[0][3]);
            w0.z = cvt_pk_bf16(aggv[1][0], aggv[1][1]);
            w0.w = cvt_pk_bf16(aggv[1][2], aggv[1][3]);
            w1.x = cvt_pk_bf16(aggv[2][0], aggv[2][1]);
            w1.y = cvt_pk_bf16(aggv[2][2], aggv[2][3]);
            w1.z = cvt_pk_bf16(aggv[3][0], aggv[3][1]);
            w1.w = cvt_pk_bf16(aggv[3][2], aggv[3][3]);
            uint4* dst = (uint4*)&sAgg[pt * APITCH + l * 16];
            dst[0] = w0; dst[1] = w1;
        }
    }
    __syncthreads();

    // ---- Phase C: out[pt][o] = sum_k' agg[pt][k'] * WB[k'][o] ----
    // wave w handles ntiles 2w, 2w+1; 32 K-steps; no barriers.
    {
        f32x4 c0 = {0.f, 0.f, 0.f, 0.f};
        f32x4 c1 = {0.f, 0.f, 0.f, 0.f};
        const unsigned short* aggRow = &sAgg[(l & 15) * APITCH + q * 8];
        const unsigned short* wb0 = &WB[(size_t)(2 * w * 64 + l) * 8];
        #pragma unroll 2
        for (int s = 0; s < KSTEPS; ++s) {
            const bf16x8 a  = *(const bf16x8*)&aggRow[s * 32];
            const bf16x8 b0 = *(const bf16x8*)&wb0[(size_t)s * 4096];
            const bf16x8 b1 = *(const bf16x8*)&wb0[(size_t)s * 4096 + 512];
            c0 = __builtin_amdgcn_mfma_f32_16x16x32_bf16(a, b0, c0, 0, 0, 0);
            c1 = __builtin_amdgcn_mfma_f32_16x16x32_bf16(a, b1, c1, 0, 0, 0);
        }
        const int rbase = q * 4;
        const int o0 = 2 * w * 16 + (l & 15);
        #pragma unroll
        for (int r = 0; r < 4; ++r) {
            const int pt = rbase + r;
            out[(size_t)(n0 + pt) * CO + o0]      = c0[r];
            out[(size_t)(n0 + pt) * CO + o0 + 16] = c1[r];
        }
    }
}

extern "C" void kernel_launch(void* const* d_in, const int* in_sizes, int n_in,
                              void* d_out, int out_size, void* d_ws, size_t ws_size,
                              hipStream_t stream) {
    const float* query   = (const float*)d_in[0];
    const float* support = (const float*)d_in[1];
    const int*   nidx    = (const int*)d_in[2];
    const float* feats   = (const float*)d_in[3];
    const float* W       = (const float*)d_in[4];
    const float* kp      = (const float*)d_in[5];
    float* out = (float*)d_out;
    unsigned short* WB = (unsigned short*)d_ws;   // 262144 B

    hipLaunchKernelGGL(prep_w, dim3(KSTEPS * 8 * 64 / 256), dim3(256), 0, stream, W, WB);
    hipLaunchKernelGGL(kpconv_fused, dim3(N_PTS / QB), dim3(256), 0, stream,
                       query, support, nidx, feats, WB, kp, out);
}